// Round 1
// baseline (518.742 us; speedup 1.0000x reference)
//
#include <hip/hip_runtime.h>
#include <math.h>

#define NN 50000
#define FF 96
#define EE 800000
#define OF 384          // 4 * FF concatenated output width
#define NB24 24         // FF / 4 float4s per feature row

__device__ __forceinline__ float wave_sum(float v) {
    for (int m = 32; m >= 1; m >>= 1) v += __shfl_xor(v, m, 64);
    return v;
}
__device__ __forceinline__ float wave_max(float v) {
    for (int m = 32; m >= 1; m >>= 1) v = fmaxf(v, __shfl_xor(v, m, 64));
    return v;
}

// ---- CSR build ------------------------------------------------------------
__global__ void count_deg(const int* __restrict__ idx, int* __restrict__ deg) {
    int e = blockIdx.x * blockDim.x + threadIdx.x;
    if (e < EE) atomicAdd(&deg[idx[2 * e]], 1);
}

__global__ void scan_deg(const int* __restrict__ deg, int* __restrict__ ptr) {
    __shared__ int lds[1024];
    const int n = NN;
    int t = threadIdx.x;
    int chunk = (n + 1023) >> 10;
    int s0 = t * chunk;
    int s1 = min(s0 + chunk, n);
    int s = 0;
    for (int i = s0; i < s1; ++i) s += deg[i];
    lds[t] = s;
    __syncthreads();
    for (int off = 1; off < 1024; off <<= 1) {
        int v = (t >= off) ? lds[t - off] : 0;
        __syncthreads();
        lds[t] += v;
        __syncthreads();
    }
    int run = (t == 0) ? 0 : lds[t - 1];
    for (int i = s0; i < s1; ++i) { ptr[i] = run; run += deg[i]; }
    if (t == 1023) ptr[n] = lds[1023];
}

__global__ void scatter_edges(const int* __restrict__ idx, const int* __restrict__ ptr,
                              int* __restrict__ fill, int* __restrict__ csr_col) {
    int e = blockIdx.x * blockDim.x + threadIdx.x;
    if (e < EE) {
        int r = idx[2 * e];
        int c = idx[2 * e + 1];
        int pos = atomicAdd(&fill[r], 1);
        csr_col[ptr[r] + pos] = c;
    }
}

// ---- layer 0: features = relu(self_val * node_f), scattered by self idx ---
__global__ void layer0(const float* __restrict__ node_f, const int* __restrict__ sidx,
                       const float* __restrict__ sval, float* __restrict__ out) {
    int tid = blockIdx.x * blockDim.x + threadIdx.x;
    if (tid >= NN * NB24) return;
    int i = tid / NB24, q = tid % NB24;
    int sr = sidx[2 * i];
    int sc = sidx[2 * i + 1];
    float v = sval[i];
    float4 x = ((const float4*)(node_f + (size_t)sc * FF))[q];
    float4 r;
    r.x = fmaxf(v * x.x, 0.f); r.y = fmaxf(v * x.y, 0.f);
    r.z = fmaxf(v * x.z, 0.f); r.w = fmaxf(v * x.w, 0.f);
    ((float4*)(out + (size_t)sr * OF))[q] = r;
}

// ---- per-node attention scalars for both heads ----------------------------
// ass[n] = (feats_n . k_self[0], feats_n . k_self[1])
// ann[n] = (feats_n . k_neigh[0], feats_n . k_neigh[1])
__global__ __launch_bounds__(256) void dots(const float* __restrict__ out_base, int l,
                                            const float* __restrict__ ks,
                                            const float* __restrict__ kn,
                                            float2* __restrict__ ass,
                                            float2* __restrict__ ann) {
    int wave = threadIdx.x >> 6, lane = threadIdx.x & 63;
    int n = blockIdx.x * 4 + wave;
    if (n >= NN) return;
    float4 z = make_float4(0.f, 0.f, 0.f, 0.f);
    float4 x = z, w0 = z, w1 = z, w2 = z, w3 = z;
    if (lane < NB24) {
        x  = ((const float4*)(out_base + (size_t)n * OF + l * FF))[lane];
        w0 = ((const float4*)ks)[lane];
        w1 = ((const float4*)ks)[NB24 + lane];
        w2 = ((const float4*)kn)[lane];
        w3 = ((const float4*)kn)[NB24 + lane];
    }
    float p0 = x.x * w0.x + x.y * w0.y + x.z * w0.z + x.w * w0.w;
    float p1 = x.x * w1.x + x.y * w1.y + x.z * w1.z + x.w * w1.w;
    float p2 = x.x * w2.x + x.y * w2.y + x.z * w2.z + x.w * w2.w;
    float p3 = x.x * w3.x + x.y * w3.y + x.z * w3.z + x.w * w3.w;
    p0 = wave_sum(p0); p1 = wave_sum(p1);
    p2 = wave_sum(p2); p3 = wave_sum(p3);
    if (lane == 0) {
        ass[n] = make_float2(p0, p1);
        ann[n] = make_float2(p2, p3);
    }
}

__device__ __forceinline__ float lrelu(float x) { return x > 0.f ? x : 0.2f * x; }

// ---- main GAT layer: wave per destination row -----------------------------
__global__ __launch_bounds__(256) void gat_layer(float* __restrict__ out, int l,
                                                 const int* __restrict__ ptr,
                                                 const int* __restrict__ csr_col,
                                                 const float2* __restrict__ ass,
                                                 const float2* __restrict__ ann) {
    int wave = threadIdx.x >> 6, lane = threadIdx.x & 63;
    int r = blockIdx.x * 4 + wave;
    if (r >= NN) return;
    int base = ptr[r];
    int deg = ptr[r + 1] - base;
    const float* feats = out + l * FF;   // row n at feats + n*OF
    float2 as_r = ass[r];

    // pass 1: per-head max over this row's edges
    float m0 = -1e30f, m1 = -1e30f;
    for (int j = lane; j < deg; j += 64) {
        int c = csr_col[base + j];
        float2 an = ann[c];
        m0 = fmaxf(m0, lrelu(as_r.x + an.x));
        m1 = fmaxf(m1, lrelu(as_r.y + an.y));
    }
    m0 = wave_max(m0); m1 = wave_max(m1);

    // pass 2: softmax denominators
    float d0 = 0.f, d1 = 0.f;
    for (int j = lane; j < deg; j += 64) {
        int c = csr_col[base + j];
        float2 an = ann[c];
        d0 += __expf(lrelu(as_r.x + an.x) - m0);
        d1 += __expf(lrelu(as_r.y + an.y) - m1);
    }
    d0 = wave_sum(d0); d1 = wave_sum(d1);
    float inv0 = d0 > 0.f ? 0.5f / d0 : 0.f;   // 0.5 = mean over 2 heads
    float inv1 = d1 > 0.f ? 0.5f / d1 : 0.f;

    // pass 3: combined coefficient per edge, aggregate features
    float4 acc = make_float4(0.f, 0.f, 0.f, 0.f);
    for (int j0 = 0; j0 < deg; j0 += 64) {
        int nj = min(64, deg - j0);
        float cj = 0.f;
        int colj = 0;
        if (lane < nj) {
            int c = csr_col[base + j0 + lane];
            float2 an = ann[c];
            cj = __expf(lrelu(as_r.x + an.x) - m0) * inv0 +
                 __expf(lrelu(as_r.y + an.y) - m1) * inv1;
            colj = c;
        }
        for (int k = 0; k < nj; ++k) {
            float cc = __shfl(cj, k, 64);
            int col = __shfl(colj, k, 64);
            if (lane < NB24) {
                float4 v = ((const float4*)(feats + (size_t)col * OF))[lane];
                acc.x += cc * v.x; acc.y += cc * v.y;
                acc.z += cc * v.z; acc.w += cc * v.w;
            }
        }
    }

    if (lane < NB24) {
        float4 o;
        o.x = fmaxf(acc.x, 0.f); o.y = fmaxf(acc.y, 0.f);
        o.z = fmaxf(acc.z, 0.f); o.w = fmaxf(acc.w, 0.f);
        ((float4*)(out + (size_t)r * OF + (l + 1) * FF))[lane] = o;
    }
}

extern "C" void kernel_launch(void* const* d_in, const int* in_sizes, int n_in,
                              void* d_out, int out_size, void* d_ws, size_t ws_size,
                              hipStream_t stream) {
    const float* node_f  = (const float*)d_in[0];
    const int*   adj_idx = (const int*)d_in[1];   // (1,E,2) [row,col]
    const int*   sidx    = (const int*)d_in[2];   // (N,2)
    const float* sval    = (const float*)d_in[3]; // (N,)
    const float* k_self  = (const float*)d_in[4]; // (2,96)
    const float* k_neigh = (const float*)d_in[5]; // (2,96)
    float* out = (float*)d_out;                   // (N, 384)

    char* w = (char*)d_ws;
    auto alloc = [&](size_t bytes) {
        char* p = w;
        w += (bytes + 255) & ~(size_t)255;
        return p;
    };
    int*    deg     = (int*)alloc((size_t)NN * 4);       // reused as fill
    int*    ptr     = (int*)alloc((size_t)(NN + 1) * 4);
    int*    csr_col = (int*)alloc((size_t)EE * 4);
    float2* ass     = (float2*)alloc((size_t)NN * 8);
    float2* ann     = (float2*)alloc((size_t)NN * 8);

    // CSR build (same every call; must rebuild since ws is re-poisoned)
    hipMemsetAsync(deg, 0, (size_t)NN * 4, stream);
    count_deg<<<(EE + 255) / 256, 256, 0, stream>>>(adj_idx, deg);
    scan_deg<<<1, 1024, 0, stream>>>(deg, ptr);
    hipMemsetAsync(deg, 0, (size_t)NN * 4, stream);
    scatter_edges<<<(EE + 255) / 256, 256, 0, stream>>>(adj_idx, ptr, deg, csr_col);

    // layer 0 (self-loop weighted features)
    layer0<<<(NN * NB24 + 255) / 256, 256, 0, stream>>>(node_f, sidx, sval, out);

    // 3 GAT layers; feature slices live in d_out columns [l*96, (l+1)*96)
    for (int l = 0; l < 3; ++l) {
        dots<<<(NN + 3) / 4, 256, 0, stream>>>(out, l, k_self, k_neigh, ass, ann);
        gat_layer<<<(NN + 3) / 4, 256, 0, stream>>>(out, l, ptr, csr_col, ass, ann);
    }
}

// Round 2
// 355.700 us; speedup vs baseline: 1.4584x; 1.4584x over previous
//
#include <hip/hip_runtime.h>
#include <math.h>

#define NN 50000
#define FF 96
#define EE 800000
#define OF 384          // 4 * FF concatenated output width
#define NB24 24         // FF / 4 float4s per feature row
#define SCAN_B 196      // ceil(NN / 256)

__device__ __forceinline__ float wave_sum(float v) {
    for (int m = 32; m >= 1; m >>= 1) v += __shfl_xor(v, m, 64);
    return v;
}
__device__ __forceinline__ float wave_max(float v) {
    for (int m = 32; m >= 1; m >>= 1) v = fmaxf(v, __shfl_xor(v, m, 64));
    return v;
}
__device__ __forceinline__ float lrelu(float x) { return x > 0.f ? x : 0.2f * x; }

// ---- CSR build ------------------------------------------------------------
__global__ void count_deg(const int* __restrict__ idx, int* __restrict__ deg) {
    int e = blockIdx.x * blockDim.x + threadIdx.x;
    if (e < EE) atomicAdd(&deg[idx[2 * e]], 1);
}

// hierarchical scan: block-local exclusive scan + block sums
__global__ __launch_bounds__(256) void scan_partial(const int* __restrict__ deg,
                                                    int* __restrict__ ptr,
                                                    int* __restrict__ bsum) {
    __shared__ int lds[256];
    int t = threadIdx.x, i = blockIdx.x * 256 + t;
    int v = (i < NN) ? deg[i] : 0;
    lds[t] = v;
    __syncthreads();
    for (int off = 1; off < 256; off <<= 1) {
        int u = (t >= off) ? lds[t - off] : 0;
        __syncthreads();
        lds[t] += u;
        __syncthreads();
    }
    if (i < NN) ptr[i] = lds[t] - v;           // local exclusive
    if (t == 255) bsum[blockIdx.x] = lds[255]; // block total
}

__global__ __launch_bounds__(256) void scan_bsum(const int* __restrict__ bsum,
                                                 int* __restrict__ boff) {
    __shared__ int lds[256];
    int t = threadIdx.x;
    int v = (t < SCAN_B) ? bsum[t] : 0;
    lds[t] = v;
    __syncthreads();
    for (int off = 1; off < 256; off <<= 1) {
        int u = (t >= off) ? lds[t - off] : 0;
        __syncthreads();
        lds[t] += u;
        __syncthreads();
    }
    if (t < SCAN_B) boff[t] = lds[t] - v;      // exclusive block offsets
}

__global__ __launch_bounds__(256) void scan_add(int* __restrict__ ptr,
                                                const int* __restrict__ boff) {
    int i = blockIdx.x * 256 + threadIdx.x;
    if (i < NN) ptr[i] += boff[i >> 8];
    if (i == 0) ptr[NN] = EE;
}

__global__ void scatter_edges(const int* __restrict__ idx, const int* __restrict__ ptr,
                              int* __restrict__ fill, int* __restrict__ csr_col) {
    int e = blockIdx.x * blockDim.x + threadIdx.x;
    if (e < EE) {
        int r = idx[2 * e];
        int c = idx[2 * e + 1];
        int pos = atomicAdd(&fill[r], 1);
        csr_col[ptr[r] + pos] = c;
    }
}

// ---- layer 0: relu(self_val * node_f) + fused attention dots --------------
__global__ __launch_bounds__(256) void layer0_fused(const float* __restrict__ node_f,
                                                    const int* __restrict__ sidx,
                                                    const float* __restrict__ sval,
                                                    float* __restrict__ out,
                                                    const float* __restrict__ ks,
                                                    const float* __restrict__ kn,
                                                    float2* __restrict__ ass,
                                                    float2* __restrict__ ann) {
    int wave = threadIdx.x >> 6, lane = threadIdx.x & 63;
    int n = blockIdx.x * 4 + wave;
    if (n >= NN) return;
    int sr = sidx[2 * n];
    int sc = sidx[2 * n + 1];
    float v = sval[n];
    float4 r = make_float4(0.f, 0.f, 0.f, 0.f);
    float4 w0 = r, w1 = r, w2 = r, w3 = r;
    if (lane < NB24) {
        float4 x = ((const float4*)(node_f + (size_t)sc * FF))[lane];
        r.x = fmaxf(v * x.x, 0.f); r.y = fmaxf(v * x.y, 0.f);
        r.z = fmaxf(v * x.z, 0.f); r.w = fmaxf(v * x.w, 0.f);
        ((float4*)(out + (size_t)sr * OF))[lane] = r;
        w0 = ((const float4*)ks)[lane];
        w1 = ((const float4*)ks)[NB24 + lane];
        w2 = ((const float4*)kn)[lane];
        w3 = ((const float4*)kn)[NB24 + lane];
    }
    float p0 = r.x * w0.x + r.y * w0.y + r.z * w0.z + r.w * w0.w;
    float p1 = r.x * w1.x + r.y * w1.y + r.z * w1.z + r.w * w1.w;
    float p2 = r.x * w2.x + r.y * w2.y + r.z * w2.z + r.w * w2.w;
    float p3 = r.x * w3.x + r.y * w3.y + r.z * w3.z + r.w * w3.w;
    p0 = wave_sum(p0); p1 = wave_sum(p1);
    p2 = wave_sum(p2); p3 = wave_sum(p3);
    if (lane == 0) {
        ass[sr] = make_float2(p0, p1);
        ann[sr] = make_float2(p2, p3);
    }
}

// ---- main GAT layer: wave per destination row -----------------------------
// Online softmax (single edge sweep for max+denom), register-cached chunk-0
// scores, dual-edge gather (lanes 0-23 / 32-55), fused next-layer dots.
__global__ __launch_bounds__(256) void gat_layer(float* __restrict__ out, int l,
                                                 const int* __restrict__ ptr,
                                                 const int* __restrict__ csr_col,
                                                 const float2* __restrict__ ass,
                                                 const float2* __restrict__ ann,
                                                 const float* __restrict__ ks,
                                                 const float* __restrict__ kn,
                                                 float2* __restrict__ ass_out,
                                                 float2* __restrict__ ann_out,
                                                 int write_dots) {
    int wave = threadIdx.x >> 6, lane = threadIdx.x & 63;
    int r = blockIdx.x * 4 + wave;
    if (r >= NN) return;
    int base = ptr[r];
    int deg = ptr[r + 1] - base;
    const float* feats = out + l * FF;   // row n at feats + n*OF
    float2 as_r = ass[r];

    // pass A: online per-lane softmax state; cache chunk-0 edge in registers
    float m0 = -1e30f, m1 = -1e30f, d0 = 0.f, d1 = 0.f;
    int   col0 = 0;
    float s0r = -1e30f, s1r = -1e30f;
    for (int j = lane; j < deg; j += 64) {
        int c = csr_col[base + j];
        float2 an = ann[c];
        float s0 = lrelu(as_r.x + an.x);
        float s1 = lrelu(as_r.y + an.y);
        if (j < 64) { col0 = c; s0r = s0; s1r = s1; }
        float nm0 = fmaxf(m0, s0);
        d0 = d0 * __expf(m0 - nm0) + __expf(s0 - nm0); m0 = nm0;
        float nm1 = fmaxf(m1, s1);
        d1 = d1 * __expf(m1 - nm1) + __expf(s1 - nm1); m1 = nm1;
    }
    float M0 = wave_max(m0), M1 = wave_max(m1);
    d0 = wave_sum(d0 * __expf(m0 - M0));
    d1 = wave_sum(d1 * __expf(m1 - M1));
    float inv0 = d0 > 0.f ? 0.5f / d0 : 0.f;   // 0.5 = mean over 2 heads
    float inv1 = d1 > 0.f ? 0.5f / d1 : 0.f;

    // pass B: aggregate, two edges in flight (lanes 0-23 and 32-55)
    float4 acc = make_float4(0.f, 0.f, 0.f, 0.f);
    int lsub = lane & 31, half = lane >> 5;
    for (int j0 = 0; j0 < deg; j0 += 64) {
        float cj = 0.f;
        int colj = 0;
        if (j0 == 0) {                         // common path: reuse cached scores
            cj = __expf(s0r - M0) * inv0 + __expf(s1r - M1) * inv1;
            colj = col0;
        } else {
            int j = j0 + lane;
            if (j < deg) {
                int c = csr_col[base + j];
                float2 an = ann[c];
                cj = __expf(lrelu(as_r.x + an.x) - M0) * inv0 +
                     __expf(lrelu(as_r.y + an.y) - M1) * inv1;
                colj = c;
            }
        }
        int nj = min(64, deg - j0);
        for (int k = 0; k < nj; k += 2) {
            int e = k + half;
            float cc = __shfl(cj, e, 64);
            int col = __shfl(colj, e, 64);
            if (e < nj && lsub < NB24) {
                float4 vv = ((const float4*)(feats + (size_t)col * OF))[lsub];
                acc.x += cc * vv.x; acc.y += cc * vv.y;
                acc.z += cc * vv.z; acc.w += cc * vv.w;
            }
        }
    }
    // merge the two halves (lanes 0-23 pick up lanes 32-55)
    int src = (lane & 31) + 32;
    acc.x += __shfl(acc.x, src, 64);
    acc.y += __shfl(acc.y, src, 64);
    acc.z += __shfl(acc.z, src, 64);
    acc.w += __shfl(acc.w, src, 64);

    float4 o;
    o.x = fmaxf(acc.x, 0.f); o.y = fmaxf(acc.y, 0.f);
    o.z = fmaxf(acc.z, 0.f); o.w = fmaxf(acc.w, 0.f);
    if (lane < NB24)
        ((float4*)(out + (size_t)r * OF + (l + 1) * FF))[lane] = o;

    if (write_dots) {
        float4 z = make_float4(0.f, 0.f, 0.f, 0.f);
        float4 w0 = z, w1 = z, w2 = z, w3 = z;
        if (lane < NB24) {
            w0 = ((const float4*)ks)[lane];
            w1 = ((const float4*)ks)[NB24 + lane];
            w2 = ((const float4*)kn)[lane];
            w3 = ((const float4*)kn)[NB24 + lane];
        }
        float p0 = o.x * w0.x + o.y * w0.y + o.z * w0.z + o.w * w0.w;
        float p1 = o.x * w1.x + o.y * w1.y + o.z * w1.z + o.w * w1.w;
        float p2 = o.x * w2.x + o.y * w2.y + o.z * w2.z + o.w * w2.w;
        float p3 = o.x * w3.x + o.y * w3.y + o.z * w3.z + o.w * w3.w;
        p0 = wave_sum(p0); p1 = wave_sum(p1);
        p2 = wave_sum(p2); p3 = wave_sum(p3);
        if (lane == 0) {
            ass_out[r] = make_float2(p0, p1);
            ann_out[r] = make_float2(p2, p3);
        }
    }
}

extern "C" void kernel_launch(void* const* d_in, const int* in_sizes, int n_in,
                              void* d_out, int out_size, void* d_ws, size_t ws_size,
                              hipStream_t stream) {
    const float* node_f  = (const float*)d_in[0];
    const int*   adj_idx = (const int*)d_in[1];   // (1,E,2) [row,col]
    const int*   sidx    = (const int*)d_in[2];   // (N,2)
    const float* sval    = (const float*)d_in[3]; // (N,)
    const float* k_self  = (const float*)d_in[4]; // (2,96)
    const float* k_neigh = (const float*)d_in[5]; // (2,96)
    float* out = (float*)d_out;                   // (N, 384)

    char* w = (char*)d_ws;
    auto alloc = [&](size_t bytes) {
        char* p = w;
        w += (bytes + 255) & ~(size_t)255;
        return p;
    };
    int*    deg     = (int*)alloc((size_t)2 * NN * 4); // deg + fill, one memset
    int*    fill    = deg + NN;
    int*    ptr     = (int*)alloc((size_t)(NN + 1) * 4);
    int*    csr_col = (int*)alloc((size_t)EE * 4);
    float2* ass_a   = (float2*)alloc((size_t)NN * 8);
    float2* ann_a   = (float2*)alloc((size_t)NN * 8);
    float2* ass_b   = (float2*)alloc((size_t)NN * 8);
    float2* ann_b   = (float2*)alloc((size_t)NN * 8);
    int*    bsum    = (int*)alloc((size_t)SCAN_B * 4);
    int*    boff    = (int*)alloc((size_t)SCAN_B * 4);

    // CSR build (rebuilt every call; ws is re-poisoned between calls)
    hipMemsetAsync(deg, 0, (size_t)2 * NN * 4, stream);
    count_deg<<<(EE + 255) / 256, 256, 0, stream>>>(adj_idx, deg);
    scan_partial<<<SCAN_B, 256, 0, stream>>>(deg, ptr, bsum);
    scan_bsum<<<1, 256, 0, stream>>>(bsum, boff);
    scan_add<<<SCAN_B, 256, 0, stream>>>(ptr, boff);
    scatter_edges<<<(EE + 255) / 256, 256, 0, stream>>>(adj_idx, ptr, fill, csr_col);

    // layer 0 (self-loop weighted features) + dots for layer 1
    layer0_fused<<<(NN + 3) / 4, 256, 0, stream>>>(node_f, sidx, sval, out,
                                                   k_self, k_neigh, ass_a, ann_a);

    // 3 GAT layers; feature slices live in d_out columns [l*96, (l+1)*96)
    gat_layer<<<(NN + 3) / 4, 256, 0, stream>>>(out, 0, ptr, csr_col, ass_a, ann_a,
                                                k_self, k_neigh, ass_b, ann_b, 1);
    gat_layer<<<(NN + 3) / 4, 256, 0, stream>>>(out, 1, ptr, csr_col, ass_b, ann_b,
                                                k_self, k_neigh, ass_a, ann_a, 1);
    gat_layer<<<(NN + 3) / 4, 256, 0, stream>>>(out, 2, ptr, csr_col, ass_a, ann_a,
                                                k_self, k_neigh, ass_b, ann_b, 0);
}

// Round 3
// 339.073 us; speedup vs baseline: 1.5299x; 1.0490x over previous
//
#include <hip/hip_runtime.h>
#include <math.h>

#define NN 50000
#define FF 96
#define EE 800000
#define OF 384          // 4 * FF concatenated output width
#define SCAN_B 196      // ceil(NN / 256)
#define GB 3125         // NN / 16 rows-per-block blocks (exact: 3125*16 = 50000)

__device__ __forceinline__ float grp_sum(float v) {          // 16-lane group
    for (int m = 8; m >= 1; m >>= 1) v += __shfl_xor(v, m, 64);
    return v;
}
__device__ __forceinline__ float grp_max(float v) {
    for (int m = 8; m >= 1; m >>= 1) v = fmaxf(v, __shfl_xor(v, m, 64));
    return v;
}
__device__ __forceinline__ float lrelu(float x) { return x > 0.f ? x : 0.2f * x; }
__device__ __forceinline__ void online_upd(float s, float& m, float& d) {
    float nm = fmaxf(m, s);
    d = d * __expf(m - nm) + __expf(s - nm);
    m = nm;
}

// ---- CSR build (2 edges per thread) ---------------------------------------
__global__ void count_deg(const int4* __restrict__ idx4, int* __restrict__ deg) {
    int e = blockIdx.x * blockDim.x + threadIdx.x;
    if (e < EE / 2) {
        int4 q = idx4[e];
        atomicAdd(&deg[q.x], 1);
        atomicAdd(&deg[q.z], 1);
    }
}

__global__ __launch_bounds__(256) void scan_partial(const int* __restrict__ deg,
                                                    int* __restrict__ ptr,
                                                    int* __restrict__ bsum) {
    __shared__ int lds[256];
    int t = threadIdx.x, i = blockIdx.x * 256 + t;
    int v = (i < NN) ? deg[i] : 0;
    lds[t] = v;
    __syncthreads();
    for (int off = 1; off < 256; off <<= 1) {
        int u = (t >= off) ? lds[t - off] : 0;
        __syncthreads();
        lds[t] += u;
        __syncthreads();
    }
    if (i < NN) ptr[i] = lds[t] - v;
    if (t == 255) bsum[blockIdx.x] = lds[255];
}

__global__ __launch_bounds__(256) void scan_bsum(const int* __restrict__ bsum,
                                                 int* __restrict__ boff) {
    __shared__ int lds[256];
    int t = threadIdx.x;
    int v = (t < SCAN_B) ? bsum[t] : 0;
    lds[t] = v;
    __syncthreads();
    for (int off = 1; off < 256; off <<= 1) {
        int u = (t >= off) ? lds[t - off] : 0;
        __syncthreads();
        lds[t] += u;
        __syncthreads();
    }
    if (t < SCAN_B) boff[t] = lds[t] - v;
}

__global__ __launch_bounds__(256) void scan_add(int* __restrict__ ptr,
                                                const int* __restrict__ boff) {
    int i = blockIdx.x * 256 + threadIdx.x;
    if (i < NN) ptr[i] += boff[i >> 8];
    if (i == 0) ptr[NN] = EE;
}

__global__ void scatter_edges(const int4* __restrict__ idx4, const int* __restrict__ ptr,
                              int* __restrict__ fill, int* __restrict__ csr_col) {
    int e = blockIdx.x * blockDim.x + threadIdx.x;
    if (e < EE / 2) {
        int4 q = idx4[e];
        int p0 = atomicAdd(&fill[q.x], 1);
        csr_col[ptr[q.x] + p0] = q.y;
        int p1 = atomicAdd(&fill[q.z], 1);
        csr_col[ptr[q.z] + p1] = q.w;
    }
}

// group dot helper: lane lg holds row floats {2lg,2lg+1, 32+2lg.., 64+2lg..}
__device__ __forceinline__ float grp_dot(float2 o0, float2 o1, float2 o2,
                                         const float2* __restrict__ kf2, int lg) {
    float2 w0 = kf2[lg], w1 = kf2[lg + 16], w2 = kf2[lg + 32];
    return grp_sum(o0.x * w0.x + o0.y * w0.y + o1.x * w1.x + o1.y * w1.y +
                   o2.x * w2.x + o2.y * w2.y);
}

// ---- layer 0: relu(self_val * node_f) + fused attention dots --------------
__global__ __launch_bounds__(256) void layer0_fused(const float* __restrict__ node_f,
                                                    const int* __restrict__ sidx,
                                                    const float* __restrict__ sval,
                                                    float* __restrict__ out,
                                                    const float* __restrict__ ks,
                                                    const float* __restrict__ kn,
                                                    float2* __restrict__ ass,
                                                    float2* __restrict__ ann) {
    int tid = threadIdx.x;
    int g = tid >> 4, lg = tid & 15;
    int n = blockIdx.x * 16 + g;
    if (n >= NN) return;
    int sr = sidx[2 * n];
    int sc = sidx[2 * n + 1];
    float v = sval[n];
    const float2* xp = (const float2*)(node_f + (size_t)sc * FF);
    float2 x0 = xp[lg], x1 = xp[lg + 16], x2 = xp[lg + 32];
    float2 o0, o1, o2;
    o0.x = fmaxf(v * x0.x, 0.f); o0.y = fmaxf(v * x0.y, 0.f);
    o1.x = fmaxf(v * x1.x, 0.f); o1.y = fmaxf(v * x1.y, 0.f);
    o2.x = fmaxf(v * x2.x, 0.f); o2.y = fmaxf(v * x2.y, 0.f);
    float2* op = (float2*)(out + (size_t)sr * OF);
    op[lg] = o0; op[lg + 16] = o1; op[lg + 32] = o2;
    float p0 = grp_dot(o0, o1, o2, (const float2*)ks, lg);
    float p1 = grp_dot(o0, o1, o2, (const float2*)(ks + FF), lg);
    float p2 = grp_dot(o0, o1, o2, (const float2*)kn, lg);
    float p3 = grp_dot(o0, o1, o2, (const float2*)(kn + FF), lg);
    if (lg == 0) {
        ass[sr] = make_float2(p0, p1);
        ann[sr] = make_float2(p2, p3);
    }
}

// ---- main GAT layer: 16-lane group per destination row --------------------
__device__ __forceinline__ void agg_chunk(float cj, int colj, int nj, int gbase,
                                          const float* __restrict__ feats, int lg,
                                          float2& a0, float2& a1, float2& a2) {
#pragma unroll 4
    for (int k = 0; k < nj; ++k) {
        float cc = __shfl(cj, gbase + k, 64);
        int col  = __shfl(colj, gbase + k, 64);
        const float2* vp = (const float2*)(feats + (size_t)col * OF);
        float2 v0 = vp[lg], v1 = vp[lg + 16], v2 = vp[lg + 32];
        a0.x += cc * v0.x; a0.y += cc * v0.y;
        a1.x += cc * v1.x; a1.y += cc * v1.y;
        a2.x += cc * v2.x; a2.y += cc * v2.y;
    }
}

__global__ __launch_bounds__(256) void gat_layer(float* __restrict__ out, int l,
                                                 const int* __restrict__ ptr,
                                                 const int* __restrict__ csr_col,
                                                 const float2* __restrict__ ass,
                                                 const float2* __restrict__ ann,
                                                 const float* __restrict__ ks,
                                                 const float* __restrict__ kn,
                                                 float2* __restrict__ ass_out,
                                                 float2* __restrict__ ann_out,
                                                 int write_dots) {
    int tid = threadIdx.x;
    int g = tid >> 4, lg = tid & 15;
    int gbase = ((tid >> 4) & 3) * 16;        // group base lane within wave
    int r = blockIdx.x * 16 + g;
    if (r >= NN) return;
    int base = ptr[r];
    int deg = ptr[r + 1] - base;
    const float* feats = out + l * FF;        // row n at feats + n*OF
    float2 as_r = ass[r];

    // ---- pass A: scores; chunks 0,1 (deg<=32, ~all rows) cached in scalars
    float m0 = -1e30f, m1 = -1e30f, d0 = 0.f, d1 = 0.f;
    int   c0col = 0, c1col = 0;
    float c0s0 = -1e30f, c0s1 = -1e30f, c1s0 = -1e30f, c1s1 = -1e30f;
    if (lg < deg) {
        int c = csr_col[base + lg];
        float2 an = ann[c];
        c0col = c;
        c0s0 = lrelu(as_r.x + an.x);
        c0s1 = lrelu(as_r.y + an.y);
        online_upd(c0s0, m0, d0);
        online_upd(c0s1, m1, d1);
    }
    if (deg > 16) {
        int j = 16 + lg;
        if (j < deg) {
            int c = csr_col[base + j];
            float2 an = ann[c];
            c1col = c;
            c1s0 = lrelu(as_r.x + an.x);
            c1s1 = lrelu(as_r.y + an.y);
            online_upd(c1s0, m0, d0);
            online_upd(c1s1, m1, d1);
        }
        for (int j0 = 32; j0 < deg; j0 += 16) {
            int jj = j0 + lg;
            if (jj < deg) {
                int c = csr_col[base + jj];
                float2 an = ann[c];
                online_upd(lrelu(as_r.x + an.x), m0, d0);
                online_upd(lrelu(as_r.y + an.y), m1, d1);
            }
        }
    }
    float M0 = grp_max(m0), M1 = grp_max(m1);
    d0 = grp_sum(d0 * __expf(m0 - M0));
    d1 = grp_sum(d1 * __expf(m1 - M1));
    float inv0 = d0 > 0.f ? 0.5f / d0 : 0.f;  // 0.5 = mean over 2 heads
    float inv1 = d1 > 0.f ? 0.5f / d1 : 0.f;

    // ---- pass B: aggregate
    float2 a0 = make_float2(0.f, 0.f), a1 = a0, a2 = a0;
    {
        float cj = __expf(c0s0 - M0) * inv0 + __expf(c0s1 - M1) * inv1;
        agg_chunk(cj, c0col, min(deg, 16), gbase, feats, lg, a0, a1, a2);
    }
    if (deg > 16) {
        float cj = __expf(c1s0 - M0) * inv0 + __expf(c1s1 - M1) * inv1;
        agg_chunk(cj, c1col, min(deg - 16, 16), gbase, feats, lg, a0, a1, a2);
        for (int j0 = 32; j0 < deg; j0 += 16) {
            float cjr = 0.f; int colr = 0;
            int jj = j0 + lg;
            if (jj < deg) {
                int c = csr_col[base + jj];
                float2 an = ann[c];
                cjr = __expf(lrelu(as_r.x + an.x) - M0) * inv0 +
                      __expf(lrelu(as_r.y + an.y) - M1) * inv1;
                colr = c;
            }
            agg_chunk(cjr, colr, min(deg - j0, 16), gbase, feats, lg, a0, a1, a2);
        }
    }

    float2 o0, o1, o2;
    o0.x = fmaxf(a0.x, 0.f); o0.y = fmaxf(a0.y, 0.f);
    o1.x = fmaxf(a1.x, 0.f); o1.y = fmaxf(a1.y, 0.f);
    o2.x = fmaxf(a2.x, 0.f); o2.y = fmaxf(a2.y, 0.f);
    float2* op = (float2*)(out + (size_t)r * OF + (l + 1) * FF);
    op[lg] = o0; op[lg + 16] = o1; op[lg + 32] = o2;

    if (write_dots) {
        float p0 = grp_dot(o0, o1, o2, (const float2*)ks, lg);
        float p1 = grp_dot(o0, o1, o2, (const float2*)(ks + FF), lg);
        float p2 = grp_dot(o0, o1, o2, (const float2*)kn, lg);
        float p3 = grp_dot(o0, o1, o2, (const float2*)(kn + FF), lg);
        if (lg == 0) {
            ass_out[r] = make_float2(p0, p1);
            ann_out[r] = make_float2(p2, p3);
        }
    }
}

extern "C" void kernel_launch(void* const* d_in, const int* in_sizes, int n_in,
                              void* d_out, int out_size, void* d_ws, size_t ws_size,
                              hipStream_t stream) {
    const float* node_f  = (const float*)d_in[0];
    const int*   adj_idx = (const int*)d_in[1];   // (1,E,2) [row,col] int32
    const int*   sidx    = (const int*)d_in[2];   // (N,2)
    const float* sval    = (const float*)d_in[3]; // (N,)
    const float* k_self  = (const float*)d_in[4]; // (2,96)
    const float* k_neigh = (const float*)d_in[5]; // (2,96)
    float* out = (float*)d_out;                   // (N, 384)

    char* w = (char*)d_ws;
    auto alloc = [&](size_t bytes) {
        char* p = w;
        w += (bytes + 255) & ~(size_t)255;
        return p;
    };
    int*    deg     = (int*)alloc((size_t)2 * NN * 4); // deg + fill, one memset
    int*    fill    = deg + NN;
    int*    ptr     = (int*)alloc((size_t)(NN + 1) * 4);
    int*    csr_col = (int*)alloc((size_t)EE * 4);
    float2* ass_a   = (float2*)alloc((size_t)NN * 8);
    float2* ann_a   = (float2*)alloc((size_t)NN * 8);
    float2* ass_b   = (float2*)alloc((size_t)NN * 8);
    float2* ann_b   = (float2*)alloc((size_t)NN * 8);
    int*    bsum    = (int*)alloc((size_t)SCAN_B * 4);
    int*    boff    = (int*)alloc((size_t)SCAN_B * 4);

    // CSR build (rebuilt every call; ws is re-poisoned between calls)
    hipMemsetAsync(deg, 0, (size_t)2 * NN * 4, stream);
    count_deg<<<(EE / 2 + 255) / 256, 256, 0, stream>>>((const int4*)adj_idx, deg);
    scan_partial<<<SCAN_B, 256, 0, stream>>>(deg, ptr, bsum);
    scan_bsum<<<1, 256, 0, stream>>>(bsum, boff);
    scan_add<<<SCAN_B, 256, 0, stream>>>(ptr, boff);
    scatter_edges<<<(EE / 2 + 255) / 256, 256, 0, stream>>>((const int4*)adj_idx, ptr,
                                                            fill, csr_col);

    // layer 0 (self-loop weighted features) + dots for layer 1
    layer0_fused<<<GB, 256, 0, stream>>>(node_f, sidx, sval, out,
                                         k_self, k_neigh, ass_a, ann_a);

    // 3 GAT layers; feature slices live in d_out columns [l*96, (l+1)*96)
    gat_layer<<<GB, 256, 0, stream>>>(out, 0, ptr, csr_col, ass_a, ann_a,
                                      k_self, k_neigh, ass_b, ann_b, 1);
    gat_layer<<<GB, 256, 0, stream>>>(out, 1, ptr, csr_col, ass_b, ann_b,
                                      k_self, k_neigh, ass_a, ann_a, 1);
    gat_layer<<<GB, 256, 0, stream>>>(out, 2, ptr, csr_col, ass_a, ann_a,
                                      k_self, k_neigh, ass_b, ann_b, 0);
}

// Round 4
// 296.685 us; speedup vs baseline: 1.7485x; 1.1429x over previous
//
#include <hip/hip_runtime.h>
#include <math.h>

#define NN 50000
#define FF 96
#define EE 800000
#define OF 384          // 4 * FF concatenated output width
#define SCAN_B 196      // ceil(NN / 256)
#define GB 3125         // NN / 16 rows per block
#define FBU 48          // uints per bf16 feature row (96 bf16 = 192 B)

__device__ __forceinline__ float grp_sum(float v) {          // 16-lane group
    for (int m = 8; m >= 1; m >>= 1) v += __shfl_xor(v, m, 64);
    return v;
}
__device__ __forceinline__ float grp_max(float v) {
    for (int m = 8; m >= 1; m >>= 1) v = fmaxf(v, __shfl_xor(v, m, 64));
    return v;
}
__device__ __forceinline__ float lrelu(float x) { return x > 0.f ? x : 0.2f * x; }
__device__ __forceinline__ void online_upd(float s, float& m, float& d) {
    float nm = fmaxf(m, s);
    d = d * __expf(m - nm) + __expf(s - nm);
    m = nm;
}
// bf16 pack/unpack (uint k holds elems 2k lo16, 2k+1 hi16; RNE rounding)
__device__ __forceinline__ float bf_lo(unsigned u) { return __uint_as_float(u << 16); }
__device__ __forceinline__ float bf_hi(unsigned u) { return __uint_as_float(u & 0xffff0000u); }
__device__ __forceinline__ unsigned pack_bf(float a, float b) {
    unsigned ua = __float_as_uint(a), ub = __float_as_uint(b);
    ua = ua + 0x7fffu + ((ua >> 16) & 1u);
    ub = ub + 0x7fffu + ((ub >> 16) & 1u);
    return (ua >> 16) | (ub & 0xffff0000u);
}

// ---- CSR build (4 edges per thread) ---------------------------------------
__global__ void count_deg(const int4* __restrict__ idx4, int* __restrict__ deg) {
    int e = blockIdx.x * blockDim.x + threadIdx.x;
    if (e < EE / 4) {
        int4 q0 = idx4[2 * e], q1 = idx4[2 * e + 1];
        atomicAdd(&deg[q0.x], 1);
        atomicAdd(&deg[q0.z], 1);
        atomicAdd(&deg[q1.x], 1);
        atomicAdd(&deg[q1.z], 1);
    }
}

__global__ __launch_bounds__(256) void scan_partial(const int* __restrict__ deg,
                                                    int* __restrict__ ptr,
                                                    int* __restrict__ bsum) {
    __shared__ int lds[256];
    int t = threadIdx.x, i = blockIdx.x * 256 + t;
    int v = (i < NN) ? deg[i] : 0;
    lds[t] = v;
    __syncthreads();
    for (int off = 1; off < 256; off <<= 1) {
        int u = (t >= off) ? lds[t - off] : 0;
        __syncthreads();
        lds[t] += u;
        __syncthreads();
    }
    if (i < NN) ptr[i] = lds[t] - v;
    if (t == 255) bsum[blockIdx.x] = lds[255];
}

__global__ __launch_bounds__(256) void scan_bsum(const int* __restrict__ bsum,
                                                 int* __restrict__ boff) {
    __shared__ int lds[256];
    int t = threadIdx.x;
    int v = (t < SCAN_B) ? bsum[t] : 0;
    lds[t] = v;
    __syncthreads();
    for (int off = 1; off < 256; off <<= 1) {
        int u = (t >= off) ? lds[t - off] : 0;
        __syncthreads();
        lds[t] += u;
        __syncthreads();
    }
    if (t < SCAN_B) boff[t] = lds[t] - v;
}

__global__ __launch_bounds__(256) void scan_add(int* __restrict__ ptr,
                                                const int* __restrict__ boff) {
    int i = blockIdx.x * 256 + threadIdx.x;
    if (i < NN) ptr[i] += boff[i >> 8];
    if (i == 0) ptr[NN] = EE;
}

__global__ void scatter_edges(const int4* __restrict__ idx4, const int* __restrict__ ptr,
                              int* __restrict__ fill, int* __restrict__ csr_col) {
    int e = blockIdx.x * blockDim.x + threadIdx.x;
    if (e < EE / 4) {
        int4 q0 = idx4[2 * e], q1 = idx4[2 * e + 1];
        int p0 = atomicAdd(&fill[q0.x], 1);
        csr_col[ptr[q0.x] + p0] = q0.y;
        int p1 = atomicAdd(&fill[q0.z], 1);
        csr_col[ptr[q0.z] + p1] = q0.w;
        int p2 = atomicAdd(&fill[q1.x], 1);
        csr_col[ptr[q1.x] + p2] = q1.y;
        int p3 = atomicAdd(&fill[q1.z], 1);
        csr_col[ptr[q1.z] + p3] = q1.w;
    }
}

// lane lg holds row elems {4lg..4lg+3} (float4) and {64+2lg, 65+2lg} (float2)
__device__ __forceinline__ float grp_dot6(float4 o, float2 t,
                                          const float* __restrict__ kf, int lg) {
    float4 w = ((const float4*)kf)[lg];
    float2 u = ((const float2*)(kf + 64))[lg];
    return grp_sum(o.x * w.x + o.y * w.y + o.z * w.z + o.w * w.w +
                   t.x * u.x + t.y * u.y);
}

// ---- layer 0: relu(self_val * node_f) + fused dots + bf16 copy ------------
template<int BF>
__global__ __launch_bounds__(256) void layer0_fused(const float* __restrict__ node_f,
                                                    const int* __restrict__ sidx,
                                                    const float* __restrict__ sval,
                                                    float* __restrict__ out,
                                                    unsigned* __restrict__ fb,
                                                    const float* __restrict__ ks,
                                                    const float* __restrict__ kn,
                                                    float2* __restrict__ ass,
                                                    float2* __restrict__ ann) {
    int tid = threadIdx.x;
    int g = tid >> 4, lg = tid & 15;
    int n = blockIdx.x * 16 + g;
    if (n >= NN) return;
    int sr = sidx[2 * n];
    int sc = sidx[2 * n + 1];
    float v = sval[n];
    const float* xr = node_f + (size_t)sc * FF;
    float4 x = ((const float4*)xr)[lg];
    float2 xt = ((const float2*)(xr + 64))[lg];
    float4 o; float2 ot;
    o.x = fmaxf(v * x.x, 0.f); o.y = fmaxf(v * x.y, 0.f);
    o.z = fmaxf(v * x.z, 0.f); o.w = fmaxf(v * x.w, 0.f);
    ot.x = fmaxf(v * xt.x, 0.f); ot.y = fmaxf(v * xt.y, 0.f);
    float* op = out + (size_t)sr * OF;
    ((float4*)op)[lg] = o;
    ((float2*)(op + 64))[lg] = ot;
    if (BF) {
        unsigned* fr = fb + (size_t)sr * FBU;
        uint2 p; p.x = pack_bf(o.x, o.y); p.y = pack_bf(o.z, o.w);
        ((uint2*)fr)[lg] = p;
        fr[32 + lg] = pack_bf(ot.x, ot.y);
    }
    float p0 = grp_dot6(o, ot, ks, lg);
    float p1 = grp_dot6(o, ot, ks + FF, lg);
    float p2 = grp_dot6(o, ot, kn, lg);
    float p3 = grp_dot6(o, ot, kn + FF, lg);
    if (lg == 0) {
        ass[sr] = make_float2(p0, p1);
        ann[sr] = make_float2(p2, p3);
    }
}

// ---- aggregation helpers --------------------------------------------------
template<int BF>
__device__ __forceinline__ void agg_chunk(float cj, int colj, int nj, int gbase,
                                          const float* __restrict__ feats,
                                          const unsigned* __restrict__ fb, int lg,
                                          float4& a, float2& at) {
#pragma unroll 4
    for (int k = 0; k < nj; ++k) {
        float cc = __shfl(cj, gbase + k, 64);
        int col  = __shfl(colj, gbase + k, 64);
        if (BF) {
            const unsigned* vp = fb + (size_t)col * FBU;
            uint2 q = ((const uint2*)vp)[lg];
            unsigned t = vp[32 + lg];
            a.x += cc * bf_lo(q.x); a.y += cc * bf_hi(q.x);
            a.z += cc * bf_lo(q.y); a.w += cc * bf_hi(q.y);
            at.x += cc * bf_lo(t);  at.y += cc * bf_hi(t);
        } else {
            const float* vp = feats + (size_t)col * OF;
            float4 v = ((const float4*)vp)[lg];
            float2 vt = ((const float2*)(vp + 64))[lg];
            a.x += cc * v.x; a.y += cc * v.y;
            a.z += cc * v.z; a.w += cc * v.w;
            at.x += cc * vt.x; at.y += cc * vt.y;
        }
    }
}

// ---- main GAT layer: 16-lane group per destination row --------------------
template<int BF>
__global__ __launch_bounds__(256) void gat_layer(float* __restrict__ out, int l,
                                                 const int* __restrict__ ptr,
                                                 const int* __restrict__ csr_col,
                                                 const float2* __restrict__ ass,
                                                 const float2* __restrict__ ann,
                                                 const unsigned* __restrict__ fb_in,
                                                 unsigned* __restrict__ fb_out,
                                                 const float* __restrict__ ks,
                                                 const float* __restrict__ kn,
                                                 float2* __restrict__ ass_out,
                                                 float2* __restrict__ ann_out,
                                                 int write_dots) {
    int tid = threadIdx.x;
    int g = tid >> 4, lg = tid & 15;
    int gbase = (g & 3) * 16;                 // group base lane within wave
    int r = blockIdx.x * 16 + g;
    if (r >= NN) return;
    int base = ptr[r];
    int deg = ptr[r + 1] - base;
    const float* feats = out + l * FF;        // fp32 fallback source
    float2 as_r = ass[r];

    // ---- pass A: scores; chunks 0,1 (deg<=32, ~all rows) cached in scalars
    float m0 = -1e30f, m1 = -1e30f, d0 = 0.f, d1 = 0.f;
    int   c0col = 0, c1col = 0;
    float c0s0 = -1e30f, c0s1 = -1e30f, c1s0 = -1e30f, c1s1 = -1e30f;
    if (lg < deg) {
        int c = csr_col[base + lg];
        float2 an = ann[c];
        c0col = c;
        c0s0 = lrelu(as_r.x + an.x);
        c0s1 = lrelu(as_r.y + an.y);
        online_upd(c0s0, m0, d0);
        online_upd(c0s1, m1, d1);
    }
    if (deg > 16) {
        int j = 16 + lg;
        if (j < deg) {
            int c = csr_col[base + j];
            float2 an = ann[c];
            c1col = c;
            c1s0 = lrelu(as_r.x + an.x);
            c1s1 = lrelu(as_r.y + an.y);
            online_upd(c1s0, m0, d0);
            online_upd(c1s1, m1, d1);
        }
        for (int j0 = 32; j0 < deg; j0 += 16) {
            int jj = j0 + lg;
            if (jj < deg) {
                int c = csr_col[base + jj];
                float2 an = ann[c];
                online_upd(lrelu(as_r.x + an.x), m0, d0);
                online_upd(lrelu(as_r.y + an.y), m1, d1);
            }
        }
    }
    float M0 = grp_max(m0), M1 = grp_max(m1);
    d0 = grp_sum(d0 * __expf(m0 - M0));
    d1 = grp_sum(d1 * __expf(m1 - M1));
    float inv0 = d0 > 0.f ? 0.5f / d0 : 0.f;  // 0.5 = mean over 2 heads
    float inv1 = d1 > 0.f ? 0.5f / d1 : 0.f;

    // ---- pass B: aggregate
    float4 a = make_float4(0.f, 0.f, 0.f, 0.f);
    float2 at = make_float2(0.f, 0.f);
    {
        float cj = __expf(c0s0 - M0) * inv0 + __expf(c0s1 - M1) * inv1;
        agg_chunk<BF>(cj, c0col, min(deg, 16), gbase, feats, fb_in, lg, a, at);
    }
    if (deg > 16) {
        float cj = __expf(c1s0 - M0) * inv0 + __expf(c1s1 - M1) * inv1;
        agg_chunk<BF>(cj, c1col, min(deg - 16, 16), gbase, feats, fb_in, lg, a, at);
        for (int j0 = 32; j0 < deg; j0 += 16) {
            float cjr = 0.f; int colr = 0;
            int jj = j0 + lg;
            if (jj < deg) {
                int c = csr_col[base + jj];
                float2 an = ann[c];
                cjr = __expf(lrelu(as_r.x + an.x) - M0) * inv0 +
                      __expf(lrelu(as_r.y + an.y) - M1) * inv1;
                colr = c;
            }
            agg_chunk<BF>(cjr, colr, min(deg - j0, 16), gbase, feats, fb_in, lg, a, at);
        }
    }

    float4 o; float2 ot;
    o.x = fmaxf(a.x, 0.f); o.y = fmaxf(a.y, 0.f);
    o.z = fmaxf(a.z, 0.f); o.w = fmaxf(a.w, 0.f);
    ot.x = fmaxf(at.x, 0.f); ot.y = fmaxf(at.y, 0.f);
    float* op = out + (size_t)r * OF + (l + 1) * FF;
    ((float4*)op)[lg] = o;
    ((float2*)(op + 64))[lg] = ot;
    if (BF && fb_out) {
        unsigned* fr = fb_out + (size_t)r * FBU;
        uint2 p; p.x = pack_bf(o.x, o.y); p.y = pack_bf(o.z, o.w);
        ((uint2*)fr)[lg] = p;
        fr[32 + lg] = pack_bf(ot.x, ot.y);
    }

    if (write_dots) {
        float p0 = grp_dot6(o, ot, ks, lg);
        float p1 = grp_dot6(o, ot, ks + FF, lg);
        float p2 = grp_dot6(o, ot, kn, lg);
        float p3 = grp_dot6(o, ot, kn + FF, lg);
        if (lg == 0) {
            ass_out[r] = make_float2(p0, p1);
            ann_out[r] = make_float2(p2, p3);
        }
    }
}

extern "C" void kernel_launch(void* const* d_in, const int* in_sizes, int n_in,
                              void* d_out, int out_size, void* d_ws, size_t ws_size,
                              hipStream_t stream) {
    const float* node_f  = (const float*)d_in[0];
    const int*   adj_idx = (const int*)d_in[1];   // (1,E,2) [row,col] int32
    const int*   sidx    = (const int*)d_in[2];   // (N,2)
    const float* sval    = (const float*)d_in[3]; // (N,)
    const float* k_self  = (const float*)d_in[4]; // (2,96)
    const float* k_neigh = (const float*)d_in[5]; // (2,96)
    float* out = (float*)d_out;                   // (N, 384)

    char* w = (char*)d_ws;
    auto alloc = [&](size_t bytes) {
        char* p = w;
        w += (bytes + 255) & ~(size_t)255;
        return p;
    };
    int*      deg     = (int*)alloc((size_t)2 * NN * 4); // deg + fill, one memset
    int*      fill    = deg + NN;
    int*      ptr     = (int*)alloc((size_t)(NN + 1) * 4);
    int*      csr_col = (int*)alloc((size_t)EE * 4);
    float2*   ass_a   = (float2*)alloc((size_t)NN * 8);
    float2*   ann_a   = (float2*)alloc((size_t)NN * 8);
    float2*   ass_b   = (float2*)alloc((size_t)NN * 8);
    float2*   ann_b   = (float2*)alloc((size_t)NN * 8);
    int*      bsum    = (int*)alloc((size_t)SCAN_B * 4);
    int*      boff    = (int*)alloc((size_t)SCAN_B * 4);
    unsigned* fb_a    = (unsigned*)alloc((size_t)NN * FBU * 4);
    unsigned* fb_b    = (unsigned*)alloc((size_t)NN * FBU * 4);
    // bf16-gather path only if the workspace actually holds the two fb buffers
    bool bf = (size_t)(w - (char*)d_ws) <= ws_size;

    // CSR build (rebuilt every call; ws is re-poisoned between calls)
    hipMemsetAsync(deg, 0, (size_t)2 * NN * 4, stream);
    count_deg<<<(EE / 4 + 255) / 256, 256, 0, stream>>>((const int4*)adj_idx, deg);
    scan_partial<<<SCAN_B, 256, 0, stream>>>(deg, ptr, bsum);
    scan_bsum<<<1, 256, 0, stream>>>(bsum, boff);
    scan_add<<<SCAN_B, 256, 0, stream>>>(ptr, boff);
    scatter_edges<<<(EE / 4 + 255) / 256, 256, 0, stream>>>((const int4*)adj_idx, ptr,
                                                            fill, csr_col);

    if (bf) {
        layer0_fused<1><<<GB, 256, 0, stream>>>(node_f, sidx, sval, out, fb_a,
                                                k_self, k_neigh, ass_a, ann_a);
        gat_layer<1><<<GB, 256, 0, stream>>>(out, 0, ptr, csr_col, ass_a, ann_a,
                                             fb_a, fb_b, k_self, k_neigh,
                                             ass_b, ann_b, 1);
        gat_layer<1><<<GB, 256, 0, stream>>>(out, 1, ptr, csr_col, ass_b, ann_b,
                                             fb_b, fb_a, k_self, k_neigh,
                                             ass_a, ann_a, 1);
        gat_layer<1><<<GB, 256, 0, stream>>>(out, 2, ptr, csr_col, ass_a, ann_a,
                                             fb_a, nullptr, k_self, k_neigh,
                                             ass_b, ann_b, 0);
    } else {
        layer0_fused<0><<<GB, 256, 0, stream>>>(node_f, sidx, sval, out, nullptr,
                                                k_self, k_neigh, ass_a, ann_a);
        gat_layer<0><<<GB, 256, 0, stream>>>(out, 0, ptr, csr_col, ass_a, ann_a,
                                             nullptr, nullptr, k_self, k_neigh,
                                             ass_b, ann_b, 1);
        gat_layer<0><<<GB, 256, 0, stream>>>(out, 1, ptr, csr_col, ass_b, ann_b,
                                             nullptr, nullptr, k_self, k_neigh,
                                             ass_a, ann_a, 1);
        gat_layer<0><<<GB, 256, 0, stream>>>(out, 2, ptr, csr_col, ass_a, ann_a,
                                             nullptr, nullptr, k_self, k_neigh,
                                             ass_b, ann_b, 0);
    }
}